// Round 1
// baseline (378.484 us; speedup 1.0000x reference)
//
#include <hip/hip_runtime.h>

#define N_TOK 4096
#define DIM   1024
#define NEXP  8
#define FDIM  2048
#define CAP   2048

typedef __attribute__((ext_vector_type(8))) short short8;
typedef __attribute__((ext_vector_type(4))) float f32x4;

__device__ __forceinline__ unsigned short f2bf(float f) {
  union { float f; unsigned u; } v; v.f = f;
  unsigned r = v.u + 0x7fffu + ((v.u >> 16) & 1u);
  return (unsigned short)(r >> 16);
}

__device__ __forceinline__ void async_cp16(const void* g, void* l) {
  __builtin_amdgcn_global_load_lds((const __attribute__((address_space(1))) unsigned int*)g,
                                   (__attribute__((address_space(3))) unsigned int*)l,
                                   16, 0, 0);
}

__global__ void zero_counts_k(int* counts) {
  if (threadIdx.x < NEXP) counts[threadIdx.x] = 0;
}

// in: [E][R][C] fp32  ->  out: [E][C][R] bf16
__global__ void transpose_conv_k(const float* __restrict__ in, unsigned short* __restrict__ out,
                                 int R, int C) {
  __shared__ float tile[32][33];
  int tpc = C / 32, tpr = R / 32;
  int b = blockIdx.x;
  int e = b / (tpr * tpc);
  int rem = b % (tpr * tpc);
  int rt = rem / tpc, ct = rem % tpc;
  const float* inp = in + (size_t)e * R * C;
  unsigned short* outp = out + (size_t)e * R * C;
  int tx = threadIdx.x & 31, ty = threadIdx.x >> 5;  // ty in 0..7
  int r0 = rt * 32, c0 = ct * 32;
#pragma unroll
  for (int i = 0; i < 4; i++)
    tile[ty + 8 * i][tx] = inp[(size_t)(r0 + ty + 8 * i) * C + c0 + tx];
  __syncthreads();
#pragma unroll
  for (int i = 0; i < 4; i++)
    outp[(size_t)(c0 + ty + 8 * i) * R + r0 + tx] = f2bf(tile[tx][ty + 8 * i]);
}

__global__ void build_lists_k(const float* __restrict__ routing, int* counts,
                              int* idx, float* wgt) {
  int n = blockIdx.x * blockDim.x + threadIdx.x;
  if (n >= N_TOK) return;
  for (int e = 0; e < NEXP; e++) {
    float s = routing[(size_t)n * NEXP + e];
    if (s > 0.0f) {
      int pos = atomicAdd(&counts[e], 1);
      if (pos < CAP) { idx[e * CAP + pos] = n; wgt[e * CAP + pos] = s; }
    }
  }
}

// one block per (expert, slot): gather token row -> bf16, or zero-pad to tile boundary
__global__ void gather_pad_k(const float* __restrict__ x, const int* __restrict__ counts,
                             int* __restrict__ idx, float* __restrict__ wgt,
                             unsigned short* __restrict__ Xg) {
  int b = blockIdx.x;
  int e = b / CAP, i = b % CAP;
  int cnt = counts[e];
  int cntR = min((cnt + 127) & ~127, CAP);
  if (i >= cntR) return;
  int t = threadIdx.x;  // 0..255, 4 floats each
  unsigned short* row = Xg + (size_t)(e * CAP + i) * DIM;
  if (i < cnt) {
    int n = idx[e * CAP + i];
    const float4* xr = (const float4*)(x + (size_t)n * DIM);
    float4 v = xr[t];
    ushort4 o;
    o.x = f2bf(v.x); o.y = f2bf(v.y); o.z = f2bf(v.z); o.w = f2bf(v.w);
    ((ushort4*)row)[t] = o;
  } else {
    ((ushort4*)row)[t] = make_ushort4(0, 0, 0, 0);
    if (t == 0) { idx[e * CAP + i] = 0; wgt[e * CAP + i] = 0.0f; }
  }
}

// 128x128 tile, 4 waves (each 64x64 = 4x4 frags of 16x16x32 bf16), BK=64.
// A: [E][CAP][KDIM] bf16 row-major (K contiguous). Bt: [E][NCOLS][KDIM] bf16 (B^T).
// EPI 0: H = gelu(A.B + b0) (bf16). EPI 1: atomicAdd(out[token], (A.B + b1)*wgt).
template <int EPI, int KDIM, int NCOLS>
__global__ __launch_bounds__(256, 2) void gemm_k(
    const unsigned short* __restrict__ A, const unsigned short* __restrict__ Bt,
    const float* __restrict__ bias, const int* __restrict__ counts,
    const int* __restrict__ idx, const float* __restrict__ wgt,
    unsigned short* __restrict__ Hout, float* __restrict__ out) {
  __shared__ unsigned short lsA[128 * 64];
  __shared__ unsigned short lsB[128 * 64];
  constexpr int MT = CAP / 128;
  constexpr int NT = NCOLS / 128;
  int b = blockIdx.x;
  int e = b / (MT * NT);
  int rem = b % (MT * NT);
  int mt = rem / NT, nt = rem % NT;
  int cnt = counts[e];
  int cntR = min((cnt + 127) & ~127, CAP);
  int m0 = mt * 128;
  if (m0 >= cntR) return;
  int n0 = nt * 128;

  const unsigned short* Ae = A + (size_t)e * CAP * KDIM;
  const unsigned short* Be = Bt + (size_t)e * NCOLS * KDIM;

  int tid = threadIdx.x;
  int lane = tid & 63;
  int w = tid >> 6;
  int wr = w >> 1, wc = w & 1;

  f32x4 acc[4][4];
#pragma unroll
  for (int m = 0; m < 4; m++)
#pragma unroll
    for (int n = 0; n < 4; n++) acc[m][n] = (f32x4){0.f, 0.f, 0.f, 0.f};

  // staging: 16 chunks of 1KB per tile; wave w stages chunks w*4..w*4+3.
  // lane l -> row ch*8 + (l>>3), physical 16B slot (l&7); XOR-swizzle the
  // GLOBAL source so LDS lands pre-swizzled (rule: linear dest + inv-swz src).
  int srow = lane >> 3;             // row within chunk (== row & 7)
  int scl = (lane & 7) ^ srow;      // logical 8-elem column chunk
  for (int k0 = 0; k0 < KDIM; k0 += 64) {
#pragma unroll
    for (int j = 0; j < 4; j++) {
      int ch = w * 4 + j;
      int row = ch * 8 + srow;
      async_cp16(Ae + (size_t)(m0 + row) * KDIM + k0 + scl * 8, &lsA[ch * 512]);
      async_cp16(Be + (size_t)(n0 + row) * KDIM + k0 + scl * 8, &lsB[ch * 512]);
    }
    __syncthreads();
#pragma unroll
    for (int ks = 0; ks < 2; ks++) {
      short8 av[4], bv[4];
#pragma unroll
      for (int m = 0; m < 4; m++) {
        int r = wr * 64 + m * 16 + (lane & 15);
        int cp = (ks * 4 + (lane >> 4)) ^ (r & 7);
        av[m] = *(const short8*)&lsA[r * 64 + cp * 8];
      }
#pragma unroll
      for (int n = 0; n < 4; n++) {
        int r = wc * 64 + n * 16 + (lane & 15);
        int cp = (ks * 4 + (lane >> 4)) ^ (r & 7);
        bv[n] = *(const short8*)&lsB[r * 64 + cp * 8];
      }
#pragma unroll
      for (int m = 0; m < 4; m++)
#pragma unroll
        for (int n = 0; n < 4; n++)
          acc[m][n] = __builtin_amdgcn_mfma_f32_16x16x32_bf16(av[m], bv[n], acc[m][n], 0, 0, 0);
    }
    __syncthreads();
  }

  // epilogue; C/D map: col = lane&15, row = (lane>>4)*4 + reg
  int lr = (lane >> 4) * 4;
  int lc = lane & 15;
#pragma unroll
  for (int n = 0; n < 4; n++) {
    int gc = n0 + wc * 64 + n * 16 + lc;
    float bb = bias[e * NCOLS + gc];
#pragma unroll
    for (int m = 0; m < 4; m++) {
      int gr = m0 + wr * 64 + m * 16 + lr;
      f32x4 v = acc[m][n];
#pragma unroll
      for (int r = 0; r < 4; r++) {
        int row = gr + r;
        float t = v[r] + bb;
        if (EPI == 0) {
          float g = t * 0.5f * (1.0f + erff(t * 0.70710678118f));
          Hout[(size_t)(e * CAP + row) * NCOLS + gc] = f2bf(g);
        } else {
          int token = idx[e * CAP + row];
          float wv = wgt[e * CAP + row];
          atomicAdd(out + (size_t)token * NCOLS + gc, t * wv);
        }
      }
    }
  }
}

extern "C" void kernel_launch(void* const* d_in, const int* in_sizes, int n_in,
                              void* d_out, int out_size, void* d_ws, size_t ws_size,
                              hipStream_t stream) {
  const float* x  = (const float*)d_in[0];
  const float* rt = (const float*)d_in[1];
  const float* w0 = (const float*)d_in[2];
  const float* b0 = (const float*)d_in[3];
  const float* w1 = (const float*)d_in[4];
  const float* b1 = (const float*)d_in[5];
  float* out = (float*)d_out;

  char* ws = (char*)d_ws;
  int* counts = (int*)ws;                              // 256 B reserved
  int* idx    = (int*)(ws + 256);                      // 64 KB
  float* wgt  = (float*)(ws + 256 + 65536);            // 64 KB
  unsigned short* w0T = (unsigned short*)(ws + 256 + 2 * 65536);
  unsigned short* w1T = w0T + (size_t)NEXP * DIM * FDIM;      // +33.5 MB
  unsigned short* Xg  = w1T + (size_t)NEXP * DIM * FDIM;      // +33.5 MB
  unsigned short* Hb  = Xg + (size_t)NEXP * CAP * DIM;        // +33.5 MB (H: 67 MB)

  hipMemsetAsync(d_out, 0, (size_t)N_TOK * DIM * sizeof(float), stream);
  zero_counts_k<<<1, 64, 0, stream>>>(counts);
  // w0 [E][D][F] -> w0T [E][F][D] bf16 ; w1 [E][F][D] -> w1T [E][D][F] bf16
  transpose_conv_k<<<NEXP * (DIM / 32) * (FDIM / 32), 256, 0, stream>>>(w0, w0T, DIM, FDIM);
  transpose_conv_k<<<NEXP * (FDIM / 32) * (DIM / 32), 256, 0, stream>>>(w1, w1T, FDIM, DIM);
  build_lists_k<<<N_TOK / 256, 256, 0, stream>>>(rt, counts, idx, wgt);
  gather_pad_k<<<NEXP * CAP, 256, 0, stream>>>(x, counts, idx, wgt, Xg);
  gemm_k<0, DIM, FDIM><<<NEXP * (CAP / 128) * (FDIM / 128), 256, 0, stream>>>(
      Xg, w0T, b0, counts, idx, wgt, Hb, nullptr);
  gemm_k<1, FDIM, DIM><<<NEXP * (CAP / 128) * (DIM / 128), 256, 0, stream>>>(
      Hb, w1T, b1, counts, idx, wgt, nullptr, out);
}